// Round 8
// baseline (332.256 us; speedup 1.0000x reference)
//
#include <hip/hip_runtime.h>

#define N_NODES 20000
#define N_EDGES 320000
#define E_TOT   340000   // edges + self loops
#define N_GRAPHS 64
#define N_CLASSES 5
#define SLOPE 0.2f
#define EPS_BN 1e-5f

#define CB 96            // CSR-builder blocks inside k_p1
#define NCH 209          // ceil(N_NODES / CB)

typedef _Float16 v8h __attribute__((ext_vector_type(8)));  // 8 fp16 (4 VGPRs) MFMA operand
typedef float v4f __attribute__((ext_vector_type(4)));     // 4 f32 acc
typedef _Float16 v4h __attribute__((ext_vector_type(4)));  // 4 fp16 (8 B)

#define SPQ (N_NODES * 512 / 4)
#define W1E (512 * 256)
#define W2E (256 * 256)
#define W3E (256 * 64)
#define ALZ (80000 * 4 + 20000 * 2)   // als1,ald1,als2,ald2 (4x80000) + als3,ald3 (2x20000)
#define PREP_IDS (SPQ + W1E + W2E + W3E + N_NODES + N_NODES + N_GRAPHS * 64 + ALZ)

// ctrl: 3 mini-barrier arrive arrays (96 each) at 0/96/192; release words at 384+k*256
#define RELBASE 384
#define CTRL_INTS (RELBASE + 3 * 256)

// ---------------- fused prep: weight transpose-casts + x->fp16 + zeros + gstart ----------------
__global__ __launch_bounds__(256) void k_prep(const float* __restrict__ x,
                                              _Float16* __restrict__ xh,
                                              const float* __restrict__ W1, _Float16* __restrict__ bt1,
                                              const float* __restrict__ W2, _Float16* __restrict__ bt2,
                                              const float* __restrict__ W3, _Float16* __restrict__ bt3,
                                              const int* __restrict__ batch, int* __restrict__ gstart,
                                              int* __restrict__ cnt, float* __restrict__ sums,
                                              float* __restrict__ albase) {
    int id = blockIdx.x * 256 + threadIdx.x;
    if (id < SPQ) {
        const float4 v = *(const float4*)(x + (size_t)id * 4);
        v4h h;
        h.x = (_Float16)v.x; h.y = (_Float16)v.y; h.z = (_Float16)v.z; h.w = (_Float16)v.w;
        *(v4h*)(xh + (size_t)id * 4) = h;
        return;
    }
    id -= SPQ;
    if (id < W1E) {
        const int K = 512, N = 256;
        int n = id / K, k = id - n * K;
        bt1[id] = (_Float16)W1[(size_t)k * N + n];
        return;
    }
    id -= W1E;
    if (id < W2E) {
        const int K = 256, N = 256;
        int n = id / K, k = id - n * K;
        bt2[id] = (_Float16)W2[(size_t)k * N + n];
        return;
    }
    id -= W2E;
    if (id < W3E) {
        const int K = 256, N = 64;
        int n = id / K, k = id - n * K;
        bt3[id] = (_Float16)W3[(size_t)k * N + n];
        return;
    }
    id -= W3E;
    if (id < N_NODES) {
        int i = id;
        int b = batch[i];
        if (i == 0) {
            for (int g = 0; g <= b; ++g) gstart[g] = 0;
        } else {
            int p = batch[i - 1];
            for (int g = p + 1; g <= b; ++g) gstart[g] = i;
        }
        if (i == N_NODES - 1) {
            for (int g = b + 1; g <= N_GRAPHS; ++g) gstart[g] = N_NODES;
        }
        return;
    }
    id -= N_NODES;
    if (id < N_NODES) { cnt[id] = 0; return; }
    id -= N_NODES;
    if (id < N_GRAPHS * 64) { sums[id] = 0.f; return; }
    id -= N_GRAPHS * 64;
    if (id < ALZ) albase[id] = 0.f;
}

// ---- 96-block barrier, RELAXED polling (gfx950 lesson, round-3 verified:
// agent-scope ACQUIRE atomic load lowers to load+buffer_inv PER POLL ITERATION,
// nuking the XCD L2 while laggards compute. Poll RELAXED; fence ACQUIRE once.) ----
__device__ __forceinline__ void gsync96(int* ctrl, int k, int bid) {
    int* arr = ctrl + k * CB;
    int* rel = ctrl + RELBASE + k * 256;
    __syncthreads();
    if (threadIdx.x == 0) {
        __builtin_amdgcn_fence(__ATOMIC_RELEASE, "agent");
        __hip_atomic_store(&arr[bid], 1, __ATOMIC_RELAXED, __HIP_MEMORY_SCOPE_AGENT);
    }
    if (bid == 0) {
        if ((int)threadIdx.x < CB) {
            while (__hip_atomic_load(&arr[threadIdx.x], __ATOMIC_RELAXED, __HIP_MEMORY_SCOPE_AGENT) == 0)
                __builtin_amdgcn_s_sleep(8);
        }
        __syncthreads();
        if (threadIdx.x < 8) {
            __hip_atomic_store(&rel[threadIdx.x * 32], 1, __ATOMIC_RELAXED, __HIP_MEMORY_SCOPE_AGENT);
        }
        if (threadIdx.x == 0)
            __builtin_amdgcn_fence(__ATOMIC_ACQUIRE, "agent");
    } else if (threadIdx.x == 0) {
        int* myrel = &rel[(bid & 7) * 32];
        while (__hip_atomic_load(myrel, __ATOMIC_RELAXED, __HIP_MEMORY_SCOPE_AGENT) == 0)
            __builtin_amdgcn_s_sleep(8);
        __builtin_amdgcn_fence(__ATOMIC_ACQUIRE, "agent");
    }
    __syncthreads();
}

// ---- CSR build on CB blocks (count -> two-level scan -> scatter), self-synced ----
__device__ void csr_build(const int* __restrict__ ei, int* __restrict__ cnt,
                          int* __restrict__ wptr, int* __restrict__ indptr,
                          int* __restrict__ esrc, int* __restrict__ blocksum,
                          int* __restrict__ ctrl, int bid, int tid, int* ssc) {
    // count
    for (int e = bid * 256 + tid; e < E_TOT; e += CB * 256) {
        int d = (e < N_EDGES) ? ei[N_EDGES + e] : (e - N_EDGES);
        atomicAdd(&cnt[d], 1);
    }
    gsync96(ctrl, 0, bid);
    // scan stage 1: block-local scan over NCH contiguous nodes (1 node / thread)
    const int i = bid * NCH + tid;
    const int active = (tid < NCH && i < N_NODES);
    int ls = active ? cnt[i] : 0;
    ssc[tid] = ls;
    __syncthreads();
    for (int off = 1; off < 256; off <<= 1) {
        int v = (tid >= off) ? ssc[tid - off] : 0;
        __syncthreads();
        ssc[tid] += v;
        __syncthreads();
    }
    const int epre = ssc[tid] - ls;       // exclusive prefix within block chunk
    if (tid == 255) blocksum[bid] = ssc[255];
    gsync96(ctrl, 1, bid);
    // scan stage 2: add inter-block offset, write indptr/wptr
    int boff = 0;
    for (int j = 0; j < bid; ++j) boff += blocksum[j];
    if (active) {
        const int run = boff + epre;
        indptr[i] = run;
        wptr[i] = run;
    }
    if (bid == 0 && tid == 0) indptr[N_NODES] = E_TOT;
    gsync96(ctrl, 2, bid);
    // scatter
    for (int e = bid * 256 + tid; e < E_TOT; e += CB * 256) {
        int s, d;
        if (e < N_EDGES) { s = ei[e]; d = ei[N_EDGES + e]; }
        else             { s = d = e - N_EDGES; }
        int pos = atomicAdd(&wptr[d], 1);
        esrc[pos] = s;
    }
}

// ---- f16 MFMA GEMM tile (verified structure, unchanged math) ----
template <int TN, int KK>
__device__ void gemm_tile(const _Float16* __restrict__ A,
                          const _Float16* __restrict__ Bt,
                          _Float16* __restrict__ H,
                          const float* __restrict__ aw_s,
                          const float* __restrict__ aw_d,
                          float* __restrict__ als,
                          float* __restrict__ ald,
                          int HS, int N, int bx, int by, _Float16* lbh) {
    constexpr int NTB = 2 * TN;
    constexpr int NFRAG = 2 * NTB * 64;
    constexpr int NITER = NFRAG / 256;
    const int tid = threadIdx.x;
    const int wave = tid >> 6, lane = tid & 63;
    const int wr = wave >> 1, wc = wave & 1;
    const int q = lane >> 4, r = lane & 15;
    const int m0 = bx * 64 + wr * 32;
    const int n0 = by * (NTB * 16);
    size_t abase[2];
#pragma unroll
    for (int mi = 0; mi < 2; ++mi) {
        int ar = m0 + mi * 16 + r;
        if (ar >= N_NODES) ar = N_NODES - 1;   // clamp; stores guarded
        abase[mi] = (size_t)ar * KK + q * 8;
    }
    size_t gaddr[NITER];
    int loff[NITER];
#pragma unroll
    for (int j = 0; j < NITER; ++j) {
        const int f = tid + j * 256;
        const int qq = f & 3;
        const int ss = (f >> 2) & 1;
        const int rr = (f >> 3) & 15;
        const int tt = f >> 7;
        gaddr[j] = (size_t)(n0 + tt * 16 + rr) * KK + ss * 32 + qq * 8;
        const int fi = (ss * NTB + tt) * 64 + qq * 16 + rr;
        loff[j] = fi * 8 + (fi >> 4) * 8;
    }
    v4f acc[2][TN];
#pragma unroll
    for (int mi = 0; mi < 2; ++mi)
#pragma unroll
        for (int t = 0; t < TN; ++t) acc[mi][t] = (v4f){0.f, 0.f, 0.f, 0.f};

    v8h ch[NITER];
#pragma unroll
    for (int j = 0; j < NITER; ++j) ch[j] = *(const v8h*)(Bt + gaddr[j]);

#pragma unroll
    for (int kc = 0; kc < KK; kc += 64) {
        __syncthreads();
#pragma unroll
        for (int j = 0; j < NITER; ++j) *(v8h*)&lbh[loff[j]] = ch[j];
        __syncthreads();
        if (kc + 64 < KK) {
#pragma unroll
            for (int j = 0; j < NITER; ++j) ch[j] = *(const v8h*)(Bt + gaddr[j] + kc + 64);
        }
#pragma unroll
        for (int ss = 0; ss < 2; ++ss) {
            v8h ah[2];
#pragma unroll
            for (int mi = 0; mi < 2; ++mi)
                ah[mi] = *(const v8h*)(A + abase[mi] + kc + ss * 32);
#pragma unroll
            for (int t = 0; t < TN; ++t) {
                const int fib = (ss * NTB + wc * TN + t) * 4 + q;
                const int off = (fib * 16 + r) * 8 + fib * 8;
                const v8h bh = *(const v8h*)&lbh[off];
#pragma unroll
                for (int mi = 0; mi < 2; ++mi)
                    acc[mi][t] = __builtin_amdgcn_mfma_f32_16x16x32_f16(ah[mi], bh, acc[mi][t], 0, 0, 0);
            }
        }
    }
#pragma unroll
    for (int mi = 0; mi < 2; ++mi)
#pragma unroll
        for (int t = 0; t < TN; ++t)
#pragma unroll
            for (int i = 0; i < 4; ++i) {
                const int row = m0 + mi * 16 + q * 4 + i;
                if (row < N_NODES) H[(size_t)row * N + n0 + (wc * TN + t) * 16 + r] = (_Float16)acc[mi][t][i];
            }
    const int colbase = n0 + wc * TN * 16;
    const int hd = colbase >> 6;
#pragma unroll
    for (int mi = 0; mi < 2; ++mi)
#pragma unroll
        for (int i = 0; i < 4; ++i) {
            float sp = 0.f, dp = 0.f;
#pragma unroll
            for (int t = 0; t < TN; ++t) {
                const int col = colbase + t * 16 + r;
                sp += acc[mi][t][i] * aw_s[col];
                dp += acc[mi][t][i] * aw_d[col];
            }
#pragma unroll
            for (int m = 1; m < 16; m <<= 1) {
                sp += __shfl_xor(sp, m, 64);
                dp += __shfl_xor(dp, m, 64);
            }
            const int row = m0 + mi * 16 + q * 4 + i;
            if (r == 0 && row < N_NODES) {
                atomicAdd(&als[row * HS + hd], sp);
                atomicAdd(&ald[row * HS + hd], dp);
            }
        }
}

// LDS bytes for a TN tile: NFRAG*8 halfs + skew
template <int TN>
struct LdsSize { static constexpr int halfs = (2 * 2 * TN * 64) * 8 + ((2 * 2 * TN * 64) >> 4) * 8; };

// ---- k_p1: blocks 0..95 build CSR (self-synced); blocks 96.. run GEMM1 tiles ----
// TN=2 (64x64 tiles): 1252 GEMM blocks -> ~5.3 blocks/CU in flight (round-7 k_p1
// was 2.8 blocks/CU, occupancy 14%, latency-bound). LDS 8.7KB.
__global__ __launch_bounds__(256) void k_p1(const int* __restrict__ ei,
                                            int* __restrict__ cnt, int* __restrict__ wptr,
                                            int* __restrict__ indptr, int* __restrict__ esrc,
                                            int* __restrict__ blocksum, int* __restrict__ ctrl,
                                            const _Float16* __restrict__ xh,
                                            const _Float16* __restrict__ bt1,
                                            _Float16* __restrict__ bufH,
                                            const float* __restrict__ a1s,
                                            const float* __restrict__ a1d,
                                            float* __restrict__ als1, float* __restrict__ ald1) {
    __shared__ __align__(16) _Float16 lbh[LdsSize<2>::halfs];
    const int bid = blockIdx.x;
    const int tid = threadIdx.x;
    if (bid < CB) {
        csr_build(ei, cnt, wptr, indptr, esrc, blocksum, ctrl, bid, tid, (int*)lbh);
    } else {
        const int t = bid - CB;
        if (t < 1252) gemm_tile<2, 512>(xh, bt1, bufH, a1s, a1d, als1, ald1, 4, 256,
                                        t >> 2, t & 3, lbh);
    }
}

// ---- GEMM2/3 wrapper ----
template <int TN, int KK>
__global__ __launch_bounds__(256) void k_gemm(const _Float16* __restrict__ A,
                                              const _Float16* __restrict__ Bt,
                                              _Float16* __restrict__ H,
                                              const float* __restrict__ aw_s,
                                              const float* __restrict__ aw_d,
                                              float* __restrict__ als,
                                              float* __restrict__ ald,
                                              int HS, int N) {
    __shared__ __align__(16) _Float16 lbh[LdsSize<TN>::halfs];
    gemm_tile<TN, KK>(A, Bt, H, aw_s, aw_d, als, ald, HS, N,
                      blockIdx.x, blockIdx.y, lbh);
}

// ---------------- GAT aggregate (4 heads): 1 wave/node, 8-deep gather chains ----------------
__global__ __launch_bounds__(256) void k_agg4(const _Float16* __restrict__ hin,
                                              const float* __restrict__ als,
                                              const float* __restrict__ ald,
                                              const int* __restrict__ indptr,
                                              const int* __restrict__ esrc,
                                              const float* __restrict__ bias,
                                              const float* __restrict__ gamma,
                                              const float* __restrict__ beta,
                                              const float* __restrict__ mean,
                                              const float* __restrict__ var,
                                              _Float16* __restrict__ pho) {
    const int n = blockIdx.x * 4 + (threadIdx.x >> 6);
    const int lane = threadIdx.x & 63;
    const int head = lane >> 4;
    const int c = lane * 4;
    const int beg = indptr[n], end = indptr[n + 1];
    const float aldn = ald[n * 4 + head];
    float4 acc = {0.f, 0.f, 0.f, 0.f};
    float sm = 0.f;
    int e = beg;
    for (; e + 7 < end; e += 8) {     // 8 independent gather chains in flight
        int s[8]; float vv[8]; v4h hh[8];
#pragma unroll
        for (int j = 0; j < 8; ++j) s[j] = esrc[e + j];
#pragma unroll
        for (int j = 0; j < 8; ++j) {
            vv[j] = als[s[j] * 4 + head] + aldn;
            hh[j] = *(const v4h*)(hin + (size_t)s[j] * 256 + c);
        }
#pragma unroll
        for (int j = 0; j < 8; ++j) {
            float v = vv[j];
            v = (v > 0.f) ? v : SLOPE * v;
            const float a0 = __expf(v);
            sm += a0;
            acc.x += a0 * (float)hh[j].x; acc.y += a0 * (float)hh[j].y;
            acc.z += a0 * (float)hh[j].z; acc.w += a0 * (float)hh[j].w;
        }
    }
    for (; e < end; ++e) {
        const int s0 = esrc[e];
        float v0 = als[s0 * 4 + head] + aldn;
        const v4h h0 = *(const v4h*)(hin + (size_t)s0 * 256 + c);
        v0 = (v0 > 0.f) ? v0 : SLOPE * v0;
        const float a0 = __expf(v0);
        sm += a0;
        acc.x += a0 * (float)h0.x; acc.y += a0 * (float)h0.y;
        acc.z += a0 * (float)h0.z; acc.w += a0 * (float)h0.w;
    }
    const float invd = 1.f / (sm + 1e-16f);
    float y[4] = {acc.x * invd, acc.y * invd, acc.z * invd, acc.w * invd};
    v4h oh;
#pragma unroll
    for (int i = 0; i < 4; ++i) {
        float t = y[i] + bias[c + i];
        t = (t - mean[c + i]) * rsqrtf(var[c + i] + EPS_BN) * gamma[c + i] + beta[c + i];
        t = fmaxf(t, 0.f);
        oh[i] = (_Float16)t;
    }
    *(v4h*)(pho + (size_t)n * 256 + c) = oh;
}

// ---------------- fused GAT aggregate (1 head) + bias + ReLU + pool-scatter ----------------
__global__ __launch_bounds__(256) void k_agg1(const _Float16* __restrict__ hin,
                                              const float* __restrict__ als,
                                              const float* __restrict__ ald,
                                              const int* __restrict__ indptr,
                                              const int* __restrict__ esrc,
                                              const float* __restrict__ bias,
                                              const int* __restrict__ batch,
                                              float* __restrict__ sums) {
    const int n = blockIdx.x * 4 + (threadIdx.x >> 6);
    const int lane = threadIdx.x & 63;
    const int beg = indptr[n], end = indptr[n + 1];
    const float aldn = ald[n];
    float acc = 0.f, sm = 0.f;
    int e = beg;
    for (; e + 7 < end; e += 8) {
        int s[8]; float vv[8]; float hh[8];
#pragma unroll
        for (int j = 0; j < 8; ++j) s[j] = esrc[e + j];
#pragma unroll
        for (int j = 0; j < 8; ++j) {
            vv[j] = als[s[j]] + aldn;
            hh[j] = (float)hin[(size_t)s[j] * 64 + lane];
        }
#pragma unroll
        for (int j = 0; j < 8; ++j) {
            float v = vv[j];
            v = (v > 0.f) ? v : SLOPE * v;
            const float a0 = __expf(v);
            sm += a0;
            acc += a0 * hh[j];
        }
    }
    for (; e < end; ++e) {
        const int s0 = esrc[e];
        float v0 = als[s0] + aldn;
        const float h0 = (float)hin[(size_t)s0 * 64 + lane];
        v0 = (v0 > 0.f) ? v0 : SLOPE * v0;
        const float a0 = __expf(v0);
        sm += a0;
        acc += a0 * h0;
    }
    const float invd = 1.f / (sm + 1e-16f);
    const float val = fmaxf(acc * invd + bias[lane], 0.f);
    atomicAdd(&sums[batch[n] * 64 + lane], val);
}

__global__ void k_mlp(const float* __restrict__ sums, const int* __restrict__ gstart,
                      const float* __restrict__ w1, const float* __restrict__ b1,
                      const float* __restrict__ w2, const float* __restrict__ b2,
                      float* __restrict__ outp) {
    const int g = blockIdx.x;
    const int t = threadIdx.x;  // 32
    __shared__ float hid[32];
    const int cntn = gstart[g + 1] - gstart[g];
    const float inv = 1.f / (float)max(cntn, 1);
    float acc = b1[t];
    for (int c = 0; c < 64; ++c) acc += (sums[g * 64 + c] * inv) * w1[c * 32 + t];
    hid[t] = fmaxf(acc, 0.f);
    __syncthreads();
    if (t < N_CLASSES) {
        float o = b2[t];
        for (int k = 0; k < 32; ++k) o += hid[k] * w2[k * 5 + t];
        outp[g * 5 + t] = o;
    }
}

extern "C" void kernel_launch(void* const* d_in, const int* in_sizes, int n_in,
                              void* d_out, int out_size, void* d_ws, size_t ws_size,
                              hipStream_t stream) {
    const float* x        = (const float*)d_in[0];
    const int* edge_index = (const int*)d_in[1];
    const int* batch      = (const int*)d_in[2];
    const float* W1  = (const float*)d_in[3];
    const float* a1s = (const float*)d_in[4];
    const float* a1d = (const float*)d_in[5];
    const float* b1  = (const float*)d_in[6];
    const float* g1  = (const float*)d_in[7];
    const float* be1 = (const float*)d_in[8];
    const float* mu1 = (const float*)d_in[9];
    const float* va1 = (const float*)d_in[10];
    const float* W2  = (const float*)d_in[11];
    const float* a2s = (const float*)d_in[12];
    const float* a2d = (const float*)d_in[13];
    const float* b2  = (const float*)d_in[14];
    const float* g2  = (const float*)d_in[15];
    const float* be2 = (const float*)d_in[16];
    const float* mu2 = (const float*)d_in[17];
    const float* va2 = (const float*)d_in[18];
    const float* W3  = (const float*)d_in[19];
    const float* a3s = (const float*)d_in[20];
    const float* a3d = (const float*)d_in[21];
    const float* b3  = (const float*)d_in[22];
    const float* l1w = (const float*)d_in[23];
    const float* l1b = (const float*)d_in[24];
    const float* l2w = (const float*)d_in[25];
    const float* l2b = (const float*)d_in[26];
    float* out = (float*)d_out;

    char* w = (char*)d_ws;
    size_t off = 0;
    auto alloc = [&](size_t bytes) -> void* {
        void* p = w + off;
        off += (bytes + 255) & ~(size_t)255;
        return p;
    };
    _Float16* xh   = (_Float16*)alloc((size_t)N_NODES * 512 * 2);   // layer-1 A (fp16)
    _Float16* phf  = xh;                                            // activation plane (20000x256 fp16)
    _Float16* bufH  = (_Float16*)alloc((size_t)N_NODES * 256 * 2);  // GEMM1/2 out (fp16)
    _Float16* bufH3 = (_Float16*)alloc((size_t)N_NODES * 64 * 2);   // GEMM3 out (fp16)
    _Float16* bt1 = (_Float16*)alloc((size_t)512 * 256 * 2);
    _Float16* bt2 = (_Float16*)alloc((size_t)256 * 256 * 2);
    _Float16* bt3 = (_Float16*)alloc((size_t)256 * 64 * 2);
    float* albase = (float*)alloc((size_t)ALZ * 4);  // als1,ald1,als2,ald2,als3,ald3
    float* als1 = albase;
    float* ald1 = albase + 80000;
    float* als2 = albase + 160000;
    float* ald2 = albase + 240000;
    float* als3 = albase + 320000;
    float* ald3 = albase + 340000;
    int* cnt      = (int*)alloc((size_t)N_NODES * 4);
    int* wptr     = (int*)alloc((size_t)N_NODES * 4);
    int* indptr   = (int*)alloc((size_t)(N_NODES + 1) * 4);
    int* esrc     = (int*)alloc((size_t)E_TOT * 4);
    int* gstart   = (int*)alloc((size_t)(N_GRAPHS + 1) * 4);
    float* sums   = (float*)alloc((size_t)N_GRAPHS * 64 * 4);
    int* blocksum = (int*)alloc((size_t)CB * 4);
    int* ctrl     = (int*)alloc((size_t)CTRL_INTS * 4);

    // mini-barrier cells must be zero at every graph replay
    hipMemsetAsync(ctrl, 0, (size_t)CTRL_INTS * 4, stream);

    // fused prep (weight casts, x->fp16, gstart, all zero-inits)
    k_prep<<<(PREP_IDS + 255) / 256, 256, 0, stream>>>(x, xh, W1, bt1, W2, bt2, W3, bt3,
                                                       batch, gstart, cnt, sums, albase);
    // CSR build (96 self-synced blocks) overlapped with GEMM1 (1252 64x64 tile blocks)
    k_p1<<<CB + 1252, 256, 0, stream>>>(edge_index, cnt, wptr, indptr, esrc, blocksum, ctrl,
                                        xh, bt1, bufH, a1s, a1d, als1, ald1);
    k_agg4<<<N_NODES / 4, 256, 0, stream>>>(bufH, als1, ald1, indptr, esrc, b1, g1, be1, mu1, va1, phf);
    // layer 2: 64x64 tiles for occupancy
    k_gemm<2, 256><<<dim3(313, 4), 256, 0, stream>>>(phf, bt2, bufH, a2s, a2d, als2, ald2, 4, 256);
    k_agg4<<<N_NODES / 4, 256, 0, stream>>>(bufH, als2, ald2, indptr, esrc, b2, g2, be2, mu2, va2, phf);
    // layer 3
    k_gemm<2, 256><<<dim3(313, 1), 256, 0, stream>>>(phf, bt3, bufH3, a3s, a3d, als3, ald3, 1, 64);
    k_agg1<<<N_NODES / 4, 256, 0, stream>>>(bufH3, als3, ald3, indptr, esrc, b3, batch, sums);
    // readout
    k_mlp<<<N_GRAPHS, 32, 0, stream>>>(sums, gstart, l1w, l1b, l2w, l2b, out);
}

// Round 10
// 309.525 us; speedup vs baseline: 1.0734x; 1.0734x over previous
//
#include <hip/hip_runtime.h>

#define N_NODES 20000
#define N_EDGES 320000
#define E_TOT   340000   // edges + self loops
#define N_GRAPHS 64
#define N_CLASSES 5
#define SLOPE 0.2f
#define EPS_BN 1e-5f

#define CB 96            // CSR-builder blocks inside k_p1
#define NCH 209          // ceil(N_NODES / CB)

typedef _Float16 v8h __attribute__((ext_vector_type(8)));  // 8 fp16 (4 VGPRs) MFMA operand
typedef float v4f __attribute__((ext_vector_type(4)));     // 4 f32 acc
typedef _Float16 v4h __attribute__((ext_vector_type(4)));  // 4 fp16 (8 B)

#define SPQ (N_NODES * 512 / 4)
#define W1E (512 * 256)
#define W2E (256 * 256)
#define W3E (256 * 64)
#define ALZ (80000 * 4 + 20000 * 2)   // als1,ald1,als2,ald2 (4x80000) + als3,ald3 (2x20000)
#define PREP_IDS (SPQ + W1E + W2E + W3E + N_NODES + N_NODES + N_GRAPHS * 64 + ALZ)

// ctrl: 3 mini-barrier arrive arrays (96 each) at 0/96/192; release words at 384+k*256
#define RELBASE 384
#define CTRL_INTS (RELBASE + 3 * 256)

// ---------------- fused prep: weight transpose-casts + x->fp16 + zeros + gstart ----------------
__global__ __launch_bounds__(256) void k_prep(const float* __restrict__ x,
                                              _Float16* __restrict__ xh,
                                              const float* __restrict__ W1, _Float16* __restrict__ bt1,
                                              const float* __restrict__ W2, _Float16* __restrict__ bt2,
                                              const float* __restrict__ W3, _Float16* __restrict__ bt3,
                                              const int* __restrict__ batch, int* __restrict__ gstart,
                                              int* __restrict__ cnt, float* __restrict__ sums,
                                              float* __restrict__ albase) {
    int id = blockIdx.x * 256 + threadIdx.x;
    if (id < SPQ) {
        const float4 v = *(const float4*)(x + (size_t)id * 4);
        v4h h;
        h.x = (_Float16)v.x; h.y = (_Float16)v.y; h.z = (_Float16)v.z; h.w = (_Float16)v.w;
        *(v4h*)(xh + (size_t)id * 4) = h;
        return;
    }
    id -= SPQ;
    if (id < W1E) {
        const int K = 512, N = 256;
        int n = id / K, k = id - n * K;
        bt1[id] = (_Float16)W1[(size_t)k * N + n];
        return;
    }
    id -= W1E;
    if (id < W2E) {
        const int K = 256, N = 256;
        int n = id / K, k = id - n * K;
        bt2[id] = (_Float16)W2[(size_t)k * N + n];
        return;
    }
    id -= W2E;
    if (id < W3E) {
        const int K = 256, N = 64;
        int n = id / K, k = id - n * K;
        bt3[id] = (_Float16)W3[(size_t)k * N + n];
        return;
    }
    id -= W3E;
    if (id < N_NODES) {
        int i = id;
        int b = batch[i];
        if (i == 0) {
            for (int g = 0; g <= b; ++g) gstart[g] = 0;
        } else {
            int p = batch[i - 1];
            for (int g = p + 1; g <= b; ++g) gstart[g] = i;
        }
        if (i == N_NODES - 1) {
            for (int g = b + 1; g <= N_GRAPHS; ++g) gstart[g] = N_NODES;
        }
        return;
    }
    id -= N_NODES;
    if (id < N_NODES) { cnt[id] = 0; return; }
    id -= N_NODES;
    if (id < N_GRAPHS * 64) { sums[id] = 0.f; return; }
    id -= N_GRAPHS * 64;
    if (id < ALZ) albase[id] = 0.f;
}

// ---- 96-block barrier, RELAXED polling (gfx950 lesson, round-3 verified:
// agent-scope ACQUIRE atomic load lowers to load+buffer_inv PER POLL ITERATION,
// nuking the XCD L2 while laggards compute. Poll RELAXED; fence ACQUIRE once.) ----
__device__ __forceinline__ void gsync96(int* ctrl, int k, int bid) {
    int* arr = ctrl + k * CB;
    int* rel = ctrl + RELBASE + k * 256;
    __syncthreads();
    if (threadIdx.x == 0) {
        __builtin_amdgcn_fence(__ATOMIC_RELEASE, "agent");
        __hip_atomic_store(&arr[bid], 1, __ATOMIC_RELAXED, __HIP_MEMORY_SCOPE_AGENT);
    }
    if (bid == 0) {
        if ((int)threadIdx.x < CB) {
            while (__hip_atomic_load(&arr[threadIdx.x], __ATOMIC_RELAXED, __HIP_MEMORY_SCOPE_AGENT) == 0)
                __builtin_amdgcn_s_sleep(8);
        }
        __syncthreads();
        if (threadIdx.x < 8) {
            __hip_atomic_store(&rel[threadIdx.x * 32], 1, __ATOMIC_RELAXED, __HIP_MEMORY_SCOPE_AGENT);
        }
        if (threadIdx.x == 0)
            __builtin_amdgcn_fence(__ATOMIC_ACQUIRE, "agent");
    } else if (threadIdx.x == 0) {
        int* myrel = &rel[(bid & 7) * 32];
        while (__hip_atomic_load(myrel, __ATOMIC_RELAXED, __HIP_MEMORY_SCOPE_AGENT) == 0)
            __builtin_amdgcn_s_sleep(8);
        __builtin_amdgcn_fence(__ATOMIC_ACQUIRE, "agent");
    }
    __syncthreads();
}

// ---- CSR build on CB blocks (count -> two-level scan -> scatter), self-synced ----
__device__ void csr_build(const int* __restrict__ ei, int* __restrict__ cnt,
                          int* __restrict__ wptr, int* __restrict__ indptr,
                          int* __restrict__ esrc, int* __restrict__ blocksum,
                          int* __restrict__ ctrl, int bid, int tid, int* ssc) {
    // count
    for (int e = bid * 256 + tid; e < E_TOT; e += CB * 256) {
        int d = (e < N_EDGES) ? ei[N_EDGES + e] : (e - N_EDGES);
        atomicAdd(&cnt[d], 1);
    }
    gsync96(ctrl, 0, bid);
    // scan stage 1: block-local scan over NCH contiguous nodes (1 node / thread)
    const int i = bid * NCH + tid;
    const int active = (tid < NCH && i < N_NODES);
    int ls = active ? cnt[i] : 0;
    ssc[tid] = ls;
    __syncthreads();
    for (int off = 1; off < 256; off <<= 1) {
        int v = (tid >= off) ? ssc[tid - off] : 0;
        __syncthreads();
        ssc[tid] += v;
        __syncthreads();
    }
    const int epre = ssc[tid] - ls;       // exclusive prefix within block chunk
    if (tid == 255) blocksum[bid] = ssc[255];
    gsync96(ctrl, 1, bid);
    // scan stage 2: add inter-block offset, write indptr/wptr
    int boff = 0;
    for (int j = 0; j < bid; ++j) boff += blocksum[j];
    if (active) {
        const int run = boff + epre;
        indptr[i] = run;
        wptr[i] = run;
    }
    if (bid == 0 && tid == 0) indptr[N_NODES] = E_TOT;
    gsync96(ctrl, 2, bid);
    // scatter
    for (int e = bid * 256 + tid; e < E_TOT; e += CB * 256) {
        int s, d;
        if (e < N_EDGES) { s = ei[e]; d = ei[N_EDGES + e]; }
        else             { s = d = e - N_EDGES; }
        int pos = atomicAdd(&wptr[d], 1);
        esrc[pos] = s;
    }
}

// ---- f16 MFMA GEMM tile; B register-prefetched (ch) AND A register-prefetched
// a full K-chunk ahead (ahc/ahn) so no global load sits on the MFMA critical path.
// Round-8 lesson: k_p1 is latency-bound (eff BW ~1.2 TB/s, 15% HBM, occ-insensitive);
// round-7's ah loads issued right before use were the stall. ----
template <int TN, int KK>
__device__ void gemm_tile(const _Float16* __restrict__ A,
                          const _Float16* __restrict__ Bt,
                          _Float16* __restrict__ H,
                          const float* __restrict__ aw_s,
                          const float* __restrict__ aw_d,
                          float* __restrict__ als,
                          float* __restrict__ ald,
                          int HS, int N, int bx, int by, _Float16* lbh) {
    constexpr int NTB = 2 * TN;
    constexpr int NFRAG = 2 * NTB * 64;
    constexpr int NITER = NFRAG / 256;
    const int tid = threadIdx.x;
    const int wave = tid >> 6, lane = tid & 63;
    const int wr = wave >> 1, wc = wave & 1;
    const int q = lane >> 4, r = lane & 15;
    const int m0 = bx * 64 + wr * 32;
    const int n0 = by * (NTB * 16);
    size_t abase[2];
#pragma unroll
    for (int mi = 0; mi < 2; ++mi) {
        int ar = m0 + mi * 16 + r;
        if (ar >= N_NODES) ar = N_NODES - 1;   // clamp; stores guarded
        abase[mi] = (size_t)ar * KK + q * 8;
    }
    size_t gaddr[NITER];
    int loff[NITER];
#pragma unroll
    for (int j = 0; j < NITER; ++j) {
        const int f = tid + j * 256;
        const int qq = f & 3;
        const int ss = (f >> 2) & 1;
        const int rr = (f >> 3) & 15;
        const int tt = f >> 7;
        gaddr[j] = (size_t)(n0 + tt * 16 + rr) * KK + ss * 32 + qq * 8;
        const int fi = (ss * NTB + tt) * 64 + qq * 16 + rr;
        loff[j] = fi * 8 + (fi >> 4) * 8;
    }
    v4f acc[2][TN];
#pragma unroll
    for (int mi = 0; mi < 2; ++mi)
#pragma unroll
        for (int t = 0; t < TN; ++t) acc[mi][t] = (v4f){0.f, 0.f, 0.f, 0.f};

    // preload chunk 0: B fragments (ch) and A fragments (ahc)
    v8h ch[NITER];
#pragma unroll
    for (int j = 0; j < NITER; ++j) ch[j] = *(const v8h*)(Bt + gaddr[j]);
    v8h ahc[2][2];   // [ss][mi]
#pragma unroll
    for (int ss = 0; ss < 2; ++ss)
#pragma unroll
        for (int mi = 0; mi < 2; ++mi)
            ahc[ss][mi] = *(const v8h*)(A + abase[mi] + ss * 32);

#pragma unroll
    for (int kc = 0; kc < KK; kc += 64) {
        __syncthreads();
#pragma unroll
        for (int j = 0; j < NITER; ++j) *(v8h*)&lbh[loff[j]] = ch[j];
        __syncthreads();
        v8h ahn[2][2];
        if (kc + 64 < KK) {     // prefetch next chunk (B then A); overlaps with MFMA below
#pragma unroll
            for (int j = 0; j < NITER; ++j) ch[j] = *(const v8h*)(Bt + gaddr[j] + kc + 64);
#pragma unroll
            for (int ss = 0; ss < 2; ++ss)
#pragma unroll
                for (int mi = 0; mi < 2; ++mi)
                    ahn[ss][mi] = *(const v8h*)(A + abase[mi] + kc + 64 + ss * 32);
        }
#pragma unroll
        for (int ss = 0; ss < 2; ++ss) {
#pragma unroll
            for (int t = 0; t < TN; ++t) {
                const int fib = (ss * NTB + wc * TN + t) * 4 + q;
                const int off = (fib * 16 + r) * 8 + fib * 8;
                const v8h bh = *(const v8h*)&lbh[off];
#pragma unroll
                for (int mi = 0; mi < 2; ++mi)
                    acc[mi][t] = __builtin_amdgcn_mfma_f32_16x16x32_f16(ahc[ss][mi], bh, acc[mi][t], 0, 0, 0);
            }
        }
        if (kc + 64 < KK) {
#pragma unroll
            for (int ss = 0; ss < 2; ++ss)
#pragma unroll
                for (int mi = 0; mi < 2; ++mi)
                    ahc[ss][mi] = ahn[ss][mi];
        }
    }
#pragma unroll
    for (int mi = 0; mi < 2; ++mi)
#pragma unroll
        for (int t = 0; t < TN; ++t)
#pragma unroll
            for (int i = 0; i < 4; ++i) {
                const int row = m0 + mi * 16 + q * 4 + i;
                if (row < N_NODES) H[(size_t)row * N + n0 + (wc * TN + t) * 16 + r] = (_Float16)acc[mi][t][i];
            }
    const int colbase = n0 + wc * TN * 16;
    const int hd = colbase >> 6;
#pragma unroll
    for (int mi = 0; mi < 2; ++mi)
#pragma unroll
        for (int i = 0; i < 4; ++i) {
            float sp = 0.f, dp = 0.f;
#pragma unroll
            for (int t = 0; t < TN; ++t) {
                const int col = colbase + t * 16 + r;
                sp += acc[mi][t][i] * aw_s[col];
                dp += acc[mi][t][i] * aw_d[col];
            }
#pragma unroll
            for (int m = 1; m < 16; m <<= 1) {
                sp += __shfl_xor(sp, m, 64);
                dp += __shfl_xor(dp, m, 64);
            }
            const int row = m0 + mi * 16 + q * 4 + i;
            if (r == 0 && row < N_NODES) {
                atomicAdd(&als[row * HS + hd], sp);
                atomicAdd(&ald[row * HS + hd], dp);
            }
        }
}

// ---- k_p1: blocks 0..95 build CSR (self-synced); blocks 96.. run GEMM1 tiles ----
// TN=4 (64x128 tiles, round-7 verified best: minimizes A re-reads; TN=2 cost +20MB
// FETCH and was net slower despite 2x occupancy).
__global__ __launch_bounds__(256) void k_p1(const int* __restrict__ ei,
                                            int* __restrict__ cnt, int* __restrict__ wptr,
                                            int* __restrict__ indptr, int* __restrict__ esrc,
                                            int* __restrict__ blocksum, int* __restrict__ ctrl,
                                            const _Float16* __restrict__ xh,
                                            const _Float16* __restrict__ bt1,
                                            _Float16* __restrict__ bufH,
                                            const float* __restrict__ a1s,
                                            const float* __restrict__ a1d,
                                            float* __restrict__ als1, float* __restrict__ ald1) {
    __shared__ __align__(16) char smraw[17472];
    const int bid = blockIdx.x;
    const int tid = threadIdx.x;
    if (bid < CB) {
        csr_build(ei, cnt, wptr, indptr, esrc, blocksum, ctrl, bid, tid, (int*)smraw);
    } else {
        const int t = bid - CB;
        if (t < 626) gemm_tile<4, 512>(xh, bt1, bufH, a1s, a1d, als1, ald1, 4, 256,
                                       t >> 1, t & 1, (_Float16*)smraw);
    }
}

// ---- GEMM2/3 wrapper ----
template <int TN, int KK>
__global__ __launch_bounds__(256) void k_gemm(const _Float16* __restrict__ A,
                                              const _Float16* __restrict__ Bt,
                                              _Float16* __restrict__ H,
                                              const float* __restrict__ aw_s,
                                              const float* __restrict__ aw_d,
                                              float* __restrict__ als,
                                              float* __restrict__ ald,
                                              int HS, int N) {
    __shared__ __align__(16) char smraw[17472];
    gemm_tile<TN, KK>(A, Bt, H, aw_s, aw_d, als, ald, HS, N,
                      blockIdx.x, blockIdx.y, (_Float16*)smraw);
}

// ---------------- GAT aggregate, 2 waves per node, fp16 gather, 4-wide (r7 verified) ----------------
__global__ __launch_bounds__(256) void k_agg4(const _Float16* __restrict__ hin,
                                              const float* __restrict__ als,
                                              const float* __restrict__ ald,
                                              const int* __restrict__ indptr,
                                              const int* __restrict__ esrc,
                                              const float* __restrict__ bias,
                                              const float* __restrict__ gamma,
                                              const float* __restrict__ beta,
                                              const float* __restrict__ mean,
                                              const float* __restrict__ var,
                                              _Float16* __restrict__ pho) {
    __shared__ float lacc[2][64][4];
    __shared__ float lsm[2][64];
    const int pair = threadIdx.x >> 7;          // node within block (0..1)
    const int wv   = (threadIdx.x >> 6) & 1;    // wave within pair
    const int lane = threadIdx.x & 63;
    const int n = blockIdx.x * 2 + pair;
    const int beg = indptr[n], end = indptr[n + 1];
    const int mid = beg + ((end - beg + 1) >> 1);
    const int e0 = wv ? mid : beg;
    const int e1 = wv ? end : mid;
    const int head = lane >> 4;
    const float aldn = ald[n * 4 + head];
    float4 acc = {0.f, 0.f, 0.f, 0.f};
    float sm = 0.f;
    const int c = lane * 4;
    int e = e0;
    for (; e + 3 < e1; e += 4) {       // 4 independent gather chains in flight
        const int s0 = esrc[e], s1 = esrc[e + 1], s2 = esrc[e + 2], s3 = esrc[e + 3];
        float v0 = als[s0 * 4 + head] + aldn;
        float v1 = als[s1 * 4 + head] + aldn;
        float v2 = als[s2 * 4 + head] + aldn;
        float v3 = als[s3 * 4 + head] + aldn;
        const v4h h0 = *(const v4h*)(hin + (size_t)s0 * 256 + c);
        const v4h h1 = *(const v4h*)(hin + (size_t)s1 * 256 + c);
        const v4h h2 = *(const v4h*)(hin + (size_t)s2 * 256 + c);
        const v4h h3 = *(const v4h*)(hin + (size_t)s3 * 256 + c);
        v0 = (v0 > 0.f) ? v0 : SLOPE * v0;
        v1 = (v1 > 0.f) ? v1 : SLOPE * v1;
        v2 = (v2 > 0.f) ? v2 : SLOPE * v2;
        v3 = (v3 > 0.f) ? v3 : SLOPE * v3;
        const float a0 = __expf(v0), a1 = __expf(v1), a2 = __expf(v2), a3 = __expf(v3);
        sm += (a0 + a1) + (a2 + a3);
        acc.x += a0 * (float)h0.x + a1 * (float)h1.x + a2 * (float)h2.x + a3 * (float)h3.x;
        acc.y += a0 * (float)h0.y + a1 * (float)h1.y + a2 * (float)h2.y + a3 * (float)h3.y;
        acc.z += a0 * (float)h0.z + a1 * (float)h1.z + a2 * (float)h2.z + a3 * (float)h3.z;
        acc.w += a0 * (float)h0.w + a1 * (float)h1.w + a2 * (float)h2.w + a3 * (float)h3.w;
    }
    for (; e < e1; ++e) {
        const int s0 = esrc[e];
        float v0 = als[s0 * 4 + head] + aldn;
        const v4h h0 = *(const v4h*)(hin + (size_t)s0 * 256 + c);
        v0 = (v0 > 0.f) ? v0 : SLOPE * v0;
        const float a0 = __expf(v0);
        sm += a0;
        acc.x += a0 * (float)h0.x; acc.y += a0 * (float)h0.y;
        acc.z += a0 * (float)h0.z; acc.w += a0 * (float)h0.w;
    }
    if (wv == 1) {
        lacc[pair][lane][0] = acc.x; lacc[pair][lane][1] = acc.y;
        lacc[pair][lane][2] = acc.z; lacc[pair][lane][3] = acc.w;
        lsm[pair][lane] = sm;
    }
    __syncthreads();
    if (wv == 0) {
        acc.x += lacc[pair][lane][0]; acc.y += lacc[pair][lane][1];
        acc.z += lacc[pair][lane][2]; acc.w += lacc[pair][lane][3];
        sm += lsm[pair][lane];
        const float invd = 1.f / (sm + 1e-16f);
        float y[4] = {acc.x * invd, acc.y * invd, acc.z * invd, acc.w * invd};
        v4h oh;
#pragma unroll
        for (int i = 0; i < 4; ++i) {
            float t = y[i] + bias[c + i];
            t = (t - mean[c + i]) * rsqrtf(var[c + i] + EPS_BN) * gamma[c + i] + beta[c + i];
            t = fmaxf(t, 0.f);
            oh[i] = (_Float16)t;
        }
        *(v4h*)(pho + (size_t)n * 256 + c) = oh;
    }
}

// ---------------- fused GAT aggregate (1 head) + bias + ReLU + pool-scatter ----------------
__global__ __launch_bounds__(256) void k_agg1(const _Float16* __restrict__ hin,
                                              const float* __restrict__ als,
                                              const float* __restrict__ ald,
                                              const int* __restrict__ indptr,
                                              const int* __restrict__ esrc,
                                              const float* __restrict__ bias,
                                              const int* __restrict__ batch,
                                              float* __restrict__ sums) {
    const int n = blockIdx.x * 4 + (threadIdx.x >> 6);
    const int lane = threadIdx.x & 63;
    const int beg = indptr[n], end = indptr[n + 1];
    const float aldn = ald[n];
    float acc = 0.f, sm = 0.f;
    int e = beg;
    for (; e + 3 < end; e += 4) {
        const int s0 = esrc[e], s1 = esrc[e + 1], s2 = esrc[e + 2], s3 = esrc[e + 3];
        float v0 = als[s0] + aldn;
        float v1 = als[s1] + aldn;
        float v2 = als[s2] + aldn;
        float v3 = als[s3] + aldn;
        const float h0 = (float)hin[(size_t)s0 * 64 + lane];
        const float h1 = (float)hin[(size_t)s1 * 64 + lane];
        const float h2 = (float)hin[(size_t)s2 * 64 + lane];
        const float h3 = (float)hin[(size_t)s3 * 64 + lane];
        v0 = (v0 > 0.f) ? v0 : SLOPE * v0;
        v1 = (v1 > 0.f) ? v1 : SLOPE * v1;
        v2 = (v2 > 0.f) ? v2 : SLOPE * v2;
        v3 = (v3 > 0.f) ? v3 : SLOPE * v3;
        const float a0 = __expf(v0), a1 = __expf(v1), a2 = __expf(v2), a3 = __expf(v3);
        sm += (a0 + a1) + (a2 + a3);
        acc += a0 * h0 + a1 * h1 + a2 * h2 + a3 * h3;
    }
    for (; e < end; ++e) {
        const int s0 = esrc[e];
        float v0 = als[s0] + aldn;
        const float h0 = (float)hin[(size_t)s0 * 64 + lane];
        v0 = (v0 > 0.f) ? v0 : SLOPE * v0;
        const float a0 = __expf(v0);
        sm += a0;
        acc += a0 * h0;
    }
    const float invd = 1.f / (sm + 1e-16f);
    const float val = fmaxf(acc * invd + bias[lane], 0.f);
    atomicAdd(&sums[batch[n] * 64 + lane], val);
}

__global__ void k_mlp(const float* __restrict__ sums, const int* __restrict__ gstart,
                      const float* __restrict__ w1, const float* __restrict__ b1,
                      const float* __restrict__ w2, const float* __restrict__ b2,
                      float* __restrict__ outp) {
    const int g = blockIdx.x;
    const int t = threadIdx.x;  // 32
    __shared__ float hid[32];
    const int cntn = gstart[g + 1] - gstart[g];
    const float inv = 1.f / (float)max(cntn, 1);
    float acc = b1[t];
    for (int c = 0; c < 64; ++c) acc += (sums[g * 64 + c] * inv) * w1[c * 32 + t];
    hid[t] = fmaxf(acc, 0.f);
    __syncthreads();
    if (t < N_CLASSES) {
        float o = b2[t];
        for (int k = 0; k < 32; ++k) o += hid[k] * w2[k * 5 + t];
        outp[g * 5 + t] = o;
    }
}

extern "C" void kernel_launch(void* const* d_in, const int* in_sizes, int n_in,
                              void* d_out, int out_size, void* d_ws, size_t ws_size,
                              hipStream_t stream) {
    const float* x        = (const float*)d_in[0];
    const int* edge_index = (const int*)d_in[1];
    const int* batch      = (const int*)d_in[2];
    const float* W1  = (const float*)d_in[3];
    const float* a1s = (const float*)d_in[4];
    const float* a1d = (const float*)d_in[5];
    const float* b1  = (const float*)d_in[6];
    const float* g1  = (const float*)d_in[7];
    const float* be1 = (const float*)d_in[8];
    const float* mu1 = (const float*)d_in[9];
    const float* va1 = (const float*)d_in[10];
    const float* W2  = (const float*)d_in[11];
    const float* a2s = (const float*)d_in[12];
    const float* a2d = (const float*)d_in[13];
    const float* b2  = (const float*)d_in[14];
    const float* g2  = (const float*)d_in[15];
    const float* be2 = (const float*)d_in[16];
    const float* mu2 = (const float*)d_in[17];
    const float* va2 = (const float*)d_in[18];
    const float* W3  = (const float*)d_in[19];
    const float* a3s = (const float*)d_in[20];
    const float* a3d = (const float*)d_in[21];
    const float* b3  = (const float*)d_in[22];
    const float* l1w = (const float*)d_in[23];
    const float* l1b = (const float*)d_in[24];
    const float* l2w = (const float*)d_in[25];
    const float* l2b = (const float*)d_in[26];
    float* out = (float*)d_out;

    char* w = (char*)d_ws;
    size_t off = 0;
    auto alloc = [&](size_t bytes) -> void* {
        void* p = w + off;
        off += (bytes + 255) & ~(size_t)255;
        return p;
    };
    _Float16* xh   = (_Float16*)alloc((size_t)N_NODES * 512 * 2);   // layer-1 A (fp16)
    _Float16* phf  = xh;                                            // activation plane (20000x256 fp16)
    _Float16* bufH  = (_Float16*)alloc((size_t)N_NODES * 256 * 2);  // GEMM1/2 out (fp16)
    _Float16* bufH3 = (_Float16*)alloc((size_t)N_NODES * 64 * 2);   // GEMM3 out (fp16)
    _Float16* bt1 = (_Float16*)alloc((size_t)512 * 256 * 2);
    _Float16* bt2 = (_Float16*)alloc((size_t)256 * 256 * 2);
    _Float16* bt3 = (_Float16*)alloc((size_t)256 * 64 * 2);
    float* albase = (float*)alloc((size_t)ALZ * 4);  // als1,ald1,als2,ald2,als3,ald3
    float* als1 = albase;
    float* ald1 = albase + 80000;
    float* als2 = albase + 160000;
    float* ald2 = albase + 240000;
    float* als3 = albase + 320000;
    float* ald3 = albase + 340000;
    int* cnt      = (int*)alloc((size_t)N_NODES * 4);
    int* wptr     = (int*)alloc((size_t)N_NODES * 4);
    int* indptr   = (int*)alloc((size_t)(N_NODES + 1) * 4);
    int* esrc     = (int*)alloc((size_t)E_TOT * 4);
    int* gstart   = (int*)alloc((size_t)(N_GRAPHS + 1) * 4);
    float* sums   = (float*)alloc((size_t)N_GRAPHS * 64 * 4);
    int* blocksum = (int*)alloc((size_t)CB * 4);
    int* ctrl     = (int*)alloc((size_t)CTRL_INTS * 4);

    // mini-barrier cells must be zero at every graph replay
    hipMemsetAsync(ctrl, 0, (size_t)CTRL_INTS * 4, stream);

    // fused prep (weight casts, x->fp16, gstart, all zero-inits)
    k_prep<<<(PREP_IDS + 255) / 256, 256, 0, stream>>>(x, xh, W1, bt1, W2, bt2, W3, bt3,
                                                       batch, gstart, cnt, sums, albase);
    // CSR build (96 self-synced blocks) overlapped with GEMM1 (626 tile blocks)
    k_p1<<<CB + 626, 256, 0, stream>>>(edge_index, cnt, wptr, indptr, esrc, blocksum, ctrl,
                                       xh, bt1, bufH, a1s, a1d, als1, ald1);
    k_agg4<<<N_NODES / 2, 256, 0, stream>>>(bufH, als1, ald1, indptr, esrc, b1, g1, be1, mu1, va1, phf);
    // layer 2
    k_gemm<4, 256><<<dim3(313, 2), 256, 0, stream>>>(phf, bt2, bufH, a2s, a2d, als2, ald2, 4, 256);
    k_agg4<<<N_NODES / 2, 256, 0, stream>>>(bufH, als2, ald2, indptr, esrc, b2, g2, be2, mu2, va2, phf);
    // layer 3
    k_gemm<2, 256><<<dim3(313, 1), 256, 0, stream>>>(phf, bt3, bufH3, a3s, a3d, als3, ald3, 1, 64);
    k_agg1<<<N_NODES / 4, 256, 0, stream>>>(bufH3, als3, ald3, indptr, esrc, b3, batch, sums);
    // readout
    k_mlp<<<N_GRAPHS, 32, 0, stream>>>(sums, gstart, l1w, l1b, l2w, l2b, out);
}